// Round 4
// baseline (294.284 us; speedup 1.0000x reference)
//
#include <hip/hip_runtime.h>
#include <math.h>
#include <stdint.h>

#define NN   50000
#define NPAD 50048          // 391 * 128
#define CD   256
#define DEG  16

typedef _Float16 f16;
typedef _Float16 f16x2 __attribute__((ext_vector_type(2)));
typedef _Float16 f16x4 __attribute__((ext_vector_type(4)));
typedef _Float16 f16x8 __attribute__((ext_vector_type(8)));
typedef float    f32x4 __attribute__((ext_vector_type(4)));

typedef const uint32_t __attribute__((address_space(1)))* gptr_t;
typedef uint32_t       __attribute__((address_space(3)))* lptr_t;

// ---------------------------------------------------------------------------
// h (f32) -> h16 (f16), zero-padded rows up to NPAD
// ---------------------------------------------------------------------------
__global__ __launch_bounds__(256) void conv_h(const float* __restrict__ h,
                                              f16* __restrict__ o)
{
    size_t i8 = ((size_t)blockIdx.x * 256 + threadIdx.x) * 8;
    if (i8 >= (size_t)NPAD * CD) return;
    f16x8 r;
    if (i8 < (size_t)NN * CD) {
        float4 a = ((const float4*)(h + i8))[0];
        float4 b = ((const float4*)(h + i8))[1];
        r[0] = (f16)a.x; r[1] = (f16)a.y; r[2] = (f16)a.z; r[3] = (f16)a.w;
        r[4] = (f16)b.x; r[5] = (f16)b.y; r[6] = (f16)b.z; r[7] = (f16)b.w;
    } else {
        r = (f16x8)(f16)0.f;
    }
    *(f16x8*)(o + i8) = r;
}

// ---------------------------------------------------------------------------
// W (f32 [k][n]) -> Wt (f16 [n][k]) for each of the 3 matrices
// ---------------------------------------------------------------------------
__global__ __launch_bounds__(256) void conv_w(const float* __restrict__ Wq,
                                              const float* __restrict__ Wk,
                                              const float* __restrict__ Wv,
                                              f16* __restrict__ Wt)
{
    const float* W = (blockIdx.y == 0) ? Wq : (blockIdx.y == 1) ? Wk : Wv;
    int n = blockIdx.x, k = threadIdx.x;
    Wt[(size_t)blockIdx.y * 65536 + n * 256 + k] = (f16)W[k * 256 + n];
}

// ---------------------------------------------------------------------------
// Q|K|V = h16 @ W   via mfma_f32_16x16x32_f16.   (unchanged from round 2,
// which passed the full harness incl. post-timing revalidation)
// ---------------------------------------------------------------------------
__global__ __launch_bounds__(256) void gemm16(
    const f16* __restrict__ h16, const f16* __restrict__ Wt,
    f16* __restrict__ Qo, f16* __restrict__ Ko, f16* __restrict__ Vo)
{
    __shared__ __align__(16) char lds[32768];   // A: [0,16K) B: [16K,32K)

    const int t    = threadIdx.x;
    const int lane = t & 63;
    const int wid  = t >> 6;
    const int tm   = blockIdx.x;
    const int nc0  = blockIdx.y * 128;
    const int z    = blockIdx.z;

    const f16* B = Wt + (size_t)z * 65536;
    f16* O = (z == 0) ? Qo : (z == 1) ? Ko : Vo;

    const int r15 = lane & 15;
    const int g4  = lane >> 4;
    const int l7  = lane & 7;
    const int wm  = (wid >> 1) * 64;
    const int wn  = (wid & 1) * 64;

    f32x4 acc[4][4];
#pragma unroll
    for (int i = 0; i < 4; ++i)
#pragma unroll
        for (int j = 0; j < 4; ++j) acc[i][j] = (f32x4)0.f;

    for (int kb = 0; kb < 4; ++kb) {
        // ---- stage A,B tiles (swizzled source, linear LDS dest) ----
#pragma unroll
        for (int i = 0; i < 4; ++i) {
            int L    = i * 256 + t;
            int row  = L >> 3;                    // 0..127
            int slot = (L & 7) ^ (row & 7);       // source slot
            const char* srcA = (const char*)h16 +
                ((size_t)(tm * 128 + row)) * 512 + kb * 128 + slot * 16;
            const char* srcB = (const char*)B +
                ((size_t)(nc0 + row)) * 512 + kb * 128 + slot * 16;
            uint32_t ldsOff = (uint32_t)(i * 256 + (t & 192)) * 16;
            __builtin_amdgcn_global_load_lds((gptr_t)srcA, (lptr_t)(lds + ldsOff), 16, 0, 0);
            __builtin_amdgcn_global_load_lds((gptr_t)srcB, (lptr_t)(lds + 16384 + ldsOff), 16, 0, 0);
        }
        __syncthreads();                          // drains vmcnt before barrier

        // ---- compute ----
#pragma unroll
        for (int ks = 0; ks < 2; ++ks) {
            const int sl = (ks * 4 + g4) ^ l7;    // swizzled read slot
            f16x8 a[4], b[4];
#pragma unroll
            for (int am = 0; am < 4; ++am) {
                int row = wm + am * 16 + r15;
                a[am] = *(const f16x8*)(lds + row * 128 + sl * 16);
            }
#pragma unroll
            for (int bn = 0; bn < 4; ++bn) {
                int row = wn + bn * 16 + r15;
                b[bn] = *(const f16x8*)(lds + 16384 + row * 128 + sl * 16);
            }
#pragma unroll
            for (int am = 0; am < 4; ++am)
#pragma unroll
                for (int bn = 0; bn < 4; ++bn)
                    acc[am][bn] = __builtin_amdgcn_mfma_f32_16x16x32_f16(
                        a[am], b[bn], acc[am][bn], 0, 0, 0);
        }
        if (kb < 3) __syncthreads();              // protect LDS before restage
    }

    // ---- epilogue: C row = (lane>>4)*4 + reg, col = lane&15 ----
#pragma unroll
    for (int am = 0; am < 4; ++am) {
#pragma unroll
        for (int bn = 0; bn < 4; ++bn) {
#pragma unroll
            for (int j = 0; j < 4; ++j) {
                int gm  = tm * 128 + wm + am * 16 + g4 * 4 + j;
                int col = nc0 + wn + bn * 16 + r15;
                if (gm < NN) O[(size_t)gm * 256 + col] = (f16)acc[am][bn][j];
            }
        }
    }
}

// ---------------------------------------------------------------------------
// 2D RoPE in-place on f16 Q,K. One thread per (node, head). (unchanged)
// ---------------------------------------------------------------------------
__global__ __launch_bounds__(256) void rope16(const float* __restrict__ pos,
                                              f16* __restrict__ Q,
                                              f16* __restrict__ K)
{
    int gid = blockIdx.x * 256 + threadIdx.x;
    if (gid >= NN * 8) return;
    int n = gid >> 3, hd = gid & 7;

    float cx = pos[2 * n] * 64.f;
    float cy = pos[2 * n + 1] * 64.f;
    size_t base = (size_t)n * 256 + hd * 32;

    union U { f16 h[32]; float4 v[4]; } q, k;
#pragma unroll
    for (int i = 0; i < 4; ++i) {
        q.v[i] = ((const float4*)(Q + base))[i];
        k.v[i] = ((const float4*)(K + base))[i];
    }

    const float INVF[8] = {1.f, 0.31622776601683794f, 0.1f, 0.031622776601683794f,
                           0.01f, 0.0031622776601683794f, 0.001f, 0.00031622776601683794f};
#pragma unroll
    for (int j = 0; j < 8; ++j) {
        float sx, cxs, sy, cys;
        __sincosf(cx * INVF[j], &sx, &cxs);
        __sincosf(cy * INVF[j], &sy, &cys);
        float a, b;
        a = (float)q.h[j];      b = (float)q.h[j + 8];
        q.h[j] = (f16)(a * cxs - b * sx);  q.h[j + 8] = (f16)(b * cxs + a * sx);
        a = (float)k.h[j];      b = (float)k.h[j + 8];
        k.h[j] = (f16)(a * cxs - b * sx);  k.h[j + 8] = (f16)(b * cxs + a * sx);
        a = (float)q.h[16 + j]; b = (float)q.h[24 + j];
        q.h[16 + j] = (f16)(a * cys - b * sy);  q.h[24 + j] = (f16)(b * cys + a * sy);
        a = (float)k.h[16 + j]; b = (float)k.h[24 + j];
        k.h[16 + j] = (f16)(a * cys - b * sy);  k.h[24 + j] = (f16)(b * cys + a * sy);
    }

#pragma unroll
    for (int i = 0; i < 4; ++i) {
        ((float4*)(Q + base))[i] = q.v[i];
        ((float4*)(K + base))[i] = k.v[i];
    }
}

// ---------------------------------------------------------------------------
// Edge attention + segment reduce — WAVE-LOCAL, no LDS, no barriers.
// One wave (64 lanes) per node, 4 nodes per 256-thread block.
// Phase 1: lane=(j0=l>>3, h=l&7) computes scores for edges j0 and j0+8 of
//          head h fully in-lane (16 fdot2 each) + one exp each.
// Phase 2: lane=(h2=l>>3, qd=l&7) owns f16 dims [h2*32+qd*4, +4); scores and
//          src indices pulled from phase-1 lanes via independent __shfl.
// A wave is lockstep: no ordering hazard exists in this kernel.
// ---------------------------------------------------------------------------
__global__ __launch_bounds__(256) void edge16(
    const f16* __restrict__ Q, const f16* __restrict__ K, const f16* __restrict__ V,
    const int* __restrict__ src, const int* __restrict__ dst,
    float* __restrict__ out)
{
    const int tid  = threadIdx.x;
    const int wv   = tid >> 6;                 // wave in block = node select
    const int l    = tid & 63;
    const int n    = blockIdx.x * 4 + wv;
    const int eb   = n * DEG;
    const int orow = dst[eb];                  // == n by construction

    // ---- phase 1: two scores per lane ----
    const int j0 = l >> 3, h = l & 7;
    const int sA = src[eb + j0];
    const int sB = src[eb + j0 + 8];

    const float4* Qr = (const float4*)(Q + (size_t)orow * CD + h * 32);
    const float4* KA = (const float4*)(K + (size_t)sA * CD + h * 32);
    const float4* KB = (const float4*)(K + (size_t)sB * CD + h * 32);
    float4 qv[4], ka[4], kb[4];
#pragma unroll
    for (int i = 0; i < 4; ++i) { qv[i] = Qr[i]; ka[i] = KA[i]; kb[i] = KB[i]; }

    float a0 = 0.f, a1 = 0.f, b0 = 0.f, b1 = 0.f;
#pragma unroll
    for (int i = 0; i < 4; ++i) {
        const f16x2* qp = (const f16x2*)&qv[i];
        const f16x2* ap = (const f16x2*)&ka[i];
        const f16x2* bp = (const f16x2*)&kb[i];
#if __has_builtin(__builtin_amdgcn_fdot2)
        a0 = __builtin_amdgcn_fdot2(qp[0], ap[0], a0, false);
        a1 = __builtin_amdgcn_fdot2(qp[1], ap[1], a1, false);
        a0 = __builtin_amdgcn_fdot2(qp[2], ap[2], a0, false);
        a1 = __builtin_amdgcn_fdot2(qp[3], ap[3], a1, false);
        b0 = __builtin_amdgcn_fdot2(qp[0], bp[0], b0, false);
        b1 = __builtin_amdgcn_fdot2(qp[1], bp[1], b1, false);
        b0 = __builtin_amdgcn_fdot2(qp[2], bp[2], b0, false);
        b1 = __builtin_amdgcn_fdot2(qp[3], bp[3], b1, false);
#else
#pragma unroll
        for (int u = 0; u < 4; ++u) {
            a0 += (float)qp[u].x * (float)ap[u].x + (float)qp[u].y * (float)ap[u].y;
            b0 += (float)qp[u].x * (float)bp[u].x + (float)qp[u].y * (float)bp[u].y;
        }
#endif
    }
    const float SCL = 0.17677669529663687f;
    float scA = __expf(fminf(fmaxf((a0 + a1) * SCL, -5.f), 5.f));
    float scB = __expf(fminf(fmaxf((b0 + b1) * SCL, -5.f), 5.f));

    // ---- phase 2: weighted V aggregation, scores via wave shuffle ----
    const int h2 = l >> 3, qd = l & 7;
    float ac0 = 0.f, ac1 = 0.f, ac2 = 0.f, ac3 = 0.f, z = 0.f;
#pragma unroll
    for (int j = 0; j < DEG; ++j) {
        const int srcLane = ((j & 7) << 3) | h2;
        float w = __shfl((j < 8) ? scA : scB, srcLane);   // j is compile-time
        int   s = __shfl((j < 8) ? sA  : sB,  srcLane);
        f16x4 v4 = *(const f16x4*)(V + (size_t)s * CD + h2 * 32 + qd * 4);
        ac0 += w * (float)v4[0];
        ac1 += w * (float)v4[1];
        ac2 += w * (float)v4[2];
        ac3 += w * (float)v4[3];
        z   += w;
    }
    float rz = 1.f / z;
    float4 o;
    o.x = ac0 * rz; o.y = ac1 * rz; o.z = ac2 * rz; o.w = ac3 * rz;
    *(float4*)(out + (size_t)orow * CD + h2 * 32 + qd * 4) = o;
}

// ---------------------------------------------------------------------------
extern "C" void kernel_launch(void* const* d_in, const int* in_sizes, int n_in,
                              void* d_out, int out_size, void* d_ws, size_t ws_size,
                              hipStream_t stream)
{
    const float* h   = (const float*)d_in[0];
    const float* pos = (const float*)d_in[1];
    const float* Wq  = (const float*)d_in[2];
    const float* Wk  = (const float*)d_in[3];
    const float* Wv  = (const float*)d_in[4];
    const int*   src = (const int*)d_in[5];
    const int*   dst = (const int*)d_in[6];
    float* out = (float*)d_out;

    char* w = (char*)d_ws;
    f16* h16 = (f16*)w;                                   // 25,624,576 B
    f16* Wt  = (f16*)(w + 25624576);                      //    393,216 B
    f16* Qb  = (f16*)(w + 26017792);                      // 25,624,576 B
    f16* Kb  = (f16*)(w + 51642368);
    f16* Vb  = (f16*)(w + 77266944);                      // end ~98.1 MiB

    conv_h<<<(NPAD * CD / 8 + 255) / 256, 256, 0, stream>>>(h, h16);
    conv_w<<<dim3(256, 3), 256, 0, stream>>>(Wq, Wk, Wv, Wt);
    gemm16<<<dim3(391, 2, 3), 256, 0, stream>>>(h16, Wt, Qb, Kb, Vb);
    rope16<<<(NN * 8 + 255) / 256, 256, 0, stream>>>(pos, Qb, Kb);
    edge16<<<12500, 256, 0, stream>>>(Qb, Kb, Vb, src, dst, out);
}